// Round 1
// baseline (670.435 us; speedup 1.0000x reference)
//
#include <hip/hip_runtime.h>
#include <hip/hip_bf16.h>
#include <cmath>

#define NN 4096

// ---------------- GEMM1: xs1 = x @ W1_seg + b1 ; X(8192,4096) W(4096,64) ----------------
__global__ __launch_bounds__(256) void gemm1_kernel(const float* __restrict__ X,
    const float* __restrict__ W, const float* __restrict__ bias, float* __restrict__ out) {
  __shared__ float As[64][34];   // [k][m] transposed, BK=64, BM=32, pad->34 (8B-aligned pairs)
  __shared__ float Bs[64][64];
  int tid = threadIdx.x;
  int m0 = blockIdx.x * 32;
  int tx = tid & 15, ty = tid >> 4;
  float acc[2][4] = {};
  int lr = tid >> 3;            // 0..31 : A-load row
  int lk = (tid & 7) * 8;       // A-load k base
  for (int k0 = 0; k0 < 4096; k0 += 64) {
    const float4* pa = (const float4*)(X + (size_t)(m0 + lr) * 4096 + k0 + lk);
    float4 v0 = pa[0], v1 = pa[1];
    As[lk+0][lr]=v0.x; As[lk+1][lr]=v0.y; As[lk+2][lr]=v0.z; As[lk+3][lr]=v0.w;
    As[lk+4][lr]=v1.x; As[lk+5][lr]=v1.y; As[lk+6][lr]=v1.z; As[lk+7][lr]=v1.w;
    #pragma unroll
    for (int e = 0; e < 16; ++e) {
      int idx = e * 256 + tid;
      Bs[idx >> 6][idx & 63] = W[(size_t)k0 * 64 + idx];
    }
    __syncthreads();
    #pragma unroll
    for (int kk = 0; kk < 64; ++kk) {
      float a0 = As[kk][ty*2+0], a1 = As[kk][ty*2+1];
      const float4 bv = *(const float4*)&Bs[kk][tx*4];
      acc[0][0] += a0*bv.x; acc[0][1] += a0*bv.y; acc[0][2] += a0*bv.z; acc[0][3] += a0*bv.w;
      acc[1][0] += a1*bv.x; acc[1][1] += a1*bv.y; acc[1][2] += a1*bv.z; acc[1][3] += a1*bv.w;
    }
    __syncthreads();
  }
  #pragma unroll
  for (int rr = 0; rr < 2; ++rr)
    #pragma unroll
    for (int cc = 0; cc < 4; ++cc)
      out[(size_t)(m0 + ty*2 + rr)*64 + tx*4 + cc] = acc[rr][cc] + bias[tx*4+cc];
}

// ---------------- batchnorm(B=2) + elu, elementwise over N*F features ----------------
// B=2: mean=(a+b)/2, var=d^2 with d=(a-b)/2  ->  norm_a = d/sqrt(d^2+eps), norm_b = -norm_a
__global__ void bn_elu_kernel(const float* __restrict__ src, float* __restrict__ dst,
    const float* __restrict__ gamma, const float* __restrict__ beta, int NH) {
  int idx = blockIdx.x * blockDim.x + threadIdx.x;
  if (idx >= NH) return;
  float a = src[idx], b = src[NH + idx];
  float d = 0.5f * (a - b);
  float inv = 1.0f / sqrtf(d*d + 1e-5f);
  float gm = gamma[idx], bt = beta[idx];
  float na =  d * inv * gm + bt;
  float nb = -d * inv * gm + bt;
  dst[idx]      = na > 0.f ? na : expm1f(na);
  dst[NH + idx] = nb > 0.f ? nb : expm1f(nb);
}

// ---------------- GEMM2: (8192,64)@(64,64)+bias ----------------
__global__ __launch_bounds__(256) void gemm2_kernel(const float* __restrict__ X,
    const float* __restrict__ W, const float* __restrict__ bias, float* __restrict__ out) {
  __shared__ float As[64][65];
  __shared__ float Bs[64][64];
  int tid = threadIdx.x;
  int m0 = blockIdx.x * 64;
  #pragma unroll
  for (int e = 0; e < 16; ++e) {
    int idx = e*256 + tid;
    int r = idx >> 6, c = idx & 63;
    As[r][c] = X[(size_t)m0*64 + idx];
    Bs[r][c] = W[idx];
  }
  __syncthreads();
  int tx = tid & 15, ty = tid >> 4;
  float acc[4][4] = {};
  #pragma unroll 8
  for (int kk = 0; kk < 64; ++kk) {
    float a0 = As[ty*4+0][kk], a1 = As[ty*4+1][kk], a2 = As[ty*4+2][kk], a3 = As[ty*4+3][kk];
    const float4 bv = *(const float4*)&Bs[kk][tx*4];
    acc[0][0]+=a0*bv.x; acc[0][1]+=a0*bv.y; acc[0][2]+=a0*bv.z; acc[0][3]+=a0*bv.w;
    acc[1][0]+=a1*bv.x; acc[1][1]+=a1*bv.y; acc[1][2]+=a1*bv.z; acc[1][3]+=a1*bv.w;
    acc[2][0]+=a2*bv.x; acc[2][1]+=a2*bv.y; acc[2][2]+=a2*bv.z; acc[2][3]+=a2*bv.w;
    acc[3][0]+=a3*bv.x; acc[3][1]+=a3*bv.y; acc[3][2]+=a3*bv.z; acc[3][3]+=a3*bv.w;
  }
  #pragma unroll
  for (int rr = 0; rr < 4; ++rr)
    #pragma unroll
    for (int cc = 0; cc < 4; ++cc)
      out[(size_t)(m0 + ty*4 + rr)*64 + tx*4 + cc] = acc[rr][cc] + bias[tx*4+cc];
}

// ---------------- GEMM3: g = xs @ Wg1[:64,:] + cvec[b]  ; (8192,64)@(64,128) ----------------
__global__ __launch_bounds__(256) void gemm3_kernel(const float* __restrict__ X,
    const float* __restrict__ Wg1, const float* __restrict__ cvec, float* __restrict__ out) {
  __shared__ float As[64][65];
  __shared__ float Bs[64][128];
  int tid = threadIdx.x;
  int m0 = blockIdx.x * 64;
  int b = m0 >> 12;   // 4096 rows per batch
  #pragma unroll
  for (int e = 0; e < 16; ++e) {
    int idx = e*256 + tid;
    As[idx>>6][idx&63] = X[(size_t)m0*64 + idx];
  }
  #pragma unroll
  for (int e = 0; e < 32; ++e) {
    int idx = e*256 + tid;
    Bs[idx>>7][idx&127] = Wg1[idx];   // top 64 rows of Wg1
  }
  __syncthreads();
  int tx = tid & 15, ty = tid >> 4;
  float acc0[4][4] = {};
  float acc1[4][4] = {};
  #pragma unroll 4
  for (int kk = 0; kk < 64; ++kk) {
    float a[4];
    #pragma unroll
    for (int rr = 0; rr < 4; ++rr) a[rr] = As[ty*4+rr][kk];
    const float4 b0 = *(const float4*)&Bs[kk][tx*4];
    const float4 b1 = *(const float4*)&Bs[kk][64 + tx*4];
    #pragma unroll
    for (int rr = 0; rr < 4; ++rr) {
      acc0[rr][0]+=a[rr]*b0.x; acc0[rr][1]+=a[rr]*b0.y; acc0[rr][2]+=a[rr]*b0.z; acc0[rr][3]+=a[rr]*b0.w;
      acc1[rr][0]+=a[rr]*b1.x; acc1[rr][1]+=a[rr]*b1.y; acc1[rr][2]+=a[rr]*b1.z; acc1[rr][3]+=a[rr]*b1.w;
    }
  }
  #pragma unroll
  for (int rr = 0; rr < 4; ++rr) {
    size_t rb = (size_t)(m0 + ty*4 + rr) * 128;
    #pragma unroll
    for (int cc = 0; cc < 4; ++cc) {
      int c0 = tx*4 + cc, c1 = 64 + tx*4 + cc;
      out[rb + c0] = acc0[rr][cc] + cvec[b*128 + c0];
      out[rb + c1] = acc1[rr][cc] + cvec[b*128 + c1];
    }
  }
}

// ---------------- si/sj: per row dot(g_row, a1), dot(g_row, a2) ----------------
__global__ __launch_bounds__(256) void sisj_kernel(const float* __restrict__ g,
    const float* __restrict__ a_vec, float* __restrict__ si, float* __restrict__ sj) {
  int wave = threadIdx.x >> 6, lane = threadIdx.x & 63;
  int row = blockIdx.x * 4 + wave;
  const float* gr = g + (size_t)row * 128;
  float g0 = gr[lane], g1 = gr[lane + 64];
  float v1 = g0 * a_vec[lane]       + g1 * a_vec[lane + 64];
  float v2 = g0 * a_vec[128 + lane] + g1 * a_vec[192 + lane];
  #pragma unroll
  for (int off = 32; off > 0; off >>= 1) {
    v1 += __shfl_down(v1, off);
    v2 += __shfl_down(v2, off);
  }
  if (lane == 0) { si[row] = v1; sj[row] = v2; }
}

// ---------------- sp branch part 1: ys1 = y @ W1_sp + b1_sp  (2x64 outputs) ----------------
__global__ __launch_bounds__(256) void sp1_kernel(const float* __restrict__ y,
    const float* __restrict__ W, const float* __restrict__ bias, float* __restrict__ ys1) {
  int b = blockIdx.x >> 6, h = blockIdx.x & 63;
  float s = 0.f;
  for (int k = threadIdx.x; k < NN; k += 256)
    s += y[b*NN + k] * W[(size_t)k*64 + h];
  __shared__ float red[256];
  red[threadIdx.x] = s; __syncthreads();
  for (int st = 128; st > 0; st >>= 1) {
    if (threadIdx.x < st) red[threadIdx.x] += red[threadIdx.x + st];
    __syncthreads();
  }
  if (threadIdx.x == 0) ys1[blockIdx.x] = red[0] + bias[h];
}

// ---------------- sp branch remainder + cvec = ys_final @ Wg1[64:,:]  (single block) -------
__global__ __launch_bounds__(256) void sp2_kernel(const float* __restrict__ ys1,
    const float* __restrict__ g1, const float* __restrict__ bt1,
    const float* __restrict__ W2, const float* __restrict__ b2,
    const float* __restrict__ g2, const float* __restrict__ bt2,
    const float* __restrict__ Wg1, float* __restrict__ cvec) {
  __shared__ float e1[2][64];
  __shared__ float y2[2][64];
  __shared__ float e2[2][64];
  int tid = threadIdx.x;
  if (tid < 64) {
    float a = ys1[tid], b = ys1[64 + tid];
    float d = 0.5f * (a - b);
    float inv = 1.0f / sqrtf(d*d + 1e-5f);
    float na =  d*inv*g1[tid] + bt1[tid];
    float nb = -d*inv*g1[tid] + bt1[tid];
    e1[0][tid] = na > 0.f ? na : expm1f(na);
    e1[1][tid] = nb > 0.f ? nb : expm1f(nb);
  }
  __syncthreads();
  if (tid < 128) {
    int b = tid >> 6, h = tid & 63;
    float s = b2[h];
    for (int k = 0; k < 64; ++k) s += e1[b][k] * W2[k*64 + h];
    y2[b][h] = s;
  }
  __syncthreads();
  if (tid < 64) {
    float a = y2[0][tid], b = y2[1][tid];
    float d = 0.5f * (a - b);
    float inv = 1.0f / sqrtf(d*d + 1e-5f);
    float na =  d*inv*g2[tid] + bt2[tid];
    float nb = -d*inv*g2[tid] + bt2[tid];
    e2[0][tid] = na > 0.f ? na : expm1f(na);
    e2[1][tid] = nb > 0.f ? nb : expm1f(nb);
  }
  __syncthreads();
  {
    int b = tid >> 7, o = tid & 127;
    float s = 0.f;
    for (int h = 0; h < 64; ++h) s += e2[b][h] * Wg1[(64 + h)*128 + o];
    cvec[tid] = s;
  }
}

// ---------------- attention: w=exp(leaky(si+sj)) masked; hp = (w@g)/Z  ----------------
// NOTE: e is bounded (|si|,|sj| < ~0.5 given 0.02-scale weights and bn outputs in [-1,1]),
// so exp(e) cannot overflow -> skip the max-subtraction pass (softmax ratio identical).
__global__ __launch_bounds__(256) void att_kernel(const int* __restrict__ adj,
    const float* __restrict__ si, const float* __restrict__ sj,
    const float* __restrict__ g, float* __restrict__ hp) {
  int b = blockIdx.y;
  int i0 = blockIdx.x * 4;
  int tid = threadIdx.x;
  __shared__ __hip_bfloat16 w[4][NN];     // 32 KB
  __shared__ float red[256];
  __shared__ float invz[4];
  __shared__ float hpart[8][4][128];      // 16 KB
  const float* sjb = sj + b * NN;
  #pragma unroll
  for (int r = 0; r < 4; ++r) {
    int row = i0 + r;
    float siv = si[b*NN + row];
    const int* arow = adj + (size_t)row * NN;
    float zp = 0.f;
    for (int j = tid; j < NN; j += 256) {
      float wv = 0.f;
      if (arow[j] != 0) {
        float e = siv + sjb[j];
        e = e >= 0.f ? e : 0.2f * e;
        wv = expf(e);
      }
      __hip_bfloat16 wb = __float2bfloat16(wv);
      w[r][j] = wb;
      zp += __bfloat162float(wb);
    }
    red[tid] = zp; __syncthreads();
    for (int st = 128; st > 0; st >>= 1) {
      if (tid < st) red[tid] += red[tid + st];
      __syncthreads();
    }
    if (tid == 0) invz[r] = red[0] > 0.f ? 1.f / red[0] : 0.f;
    __syncthreads();
  }
  // pass C: hp[r, :] = sum_j w[r][j] * g[b, j, :]
  int dg   = (tid & 31) * 4;   // 4 consecutive output dims
  int part = tid >> 5;         // 8 j-partitions of 512
  float4 acc[4];
  #pragma unroll
  for (int r = 0; r < 4; ++r) acc[r] = make_float4(0.f,0.f,0.f,0.f);
  const float* gb = g + (size_t)b * NN * 128;
  for (int j = part * 512; j < part * 512 + 512; ++j) {
    const float4 gv = *(const float4*)(gb + (size_t)j * 128 + dg);
    float w0 = __bfloat162float(w[0][j]);
    float w1 = __bfloat162float(w[1][j]);
    float w2 = __bfloat162float(w[2][j]);
    float w3 = __bfloat162float(w[3][j]);
    acc[0].x += w0*gv.x; acc[0].y += w0*gv.y; acc[0].z += w0*gv.z; acc[0].w += w0*gv.w;
    acc[1].x += w1*gv.x; acc[1].y += w1*gv.y; acc[1].z += w1*gv.z; acc[1].w += w1*gv.w;
    acc[2].x += w2*gv.x; acc[2].y += w2*gv.y; acc[2].z += w2*gv.z; acc[2].w += w2*gv.w;
    acc[3].x += w3*gv.x; acc[3].y += w3*gv.y; acc[3].z += w3*gv.z; acc[3].w += w3*gv.w;
  }
  #pragma unroll
  for (int r = 0; r < 4; ++r) *(float4*)&hpart[part][r][dg] = acc[r];
  __syncthreads();
  if (part == 0) {
    #pragma unroll
    for (int r = 0; r < 4; ++r) {
      float sx=0.f, sy=0.f, sz=0.f, sw=0.f;
      #pragma unroll
      for (int p = 0; p < 8; ++p) {
        const float4 v = *(const float4*)&hpart[p][r][dg];
        sx += v.x; sy += v.y; sz += v.z; sw += v.w;
      }
      float iz = invz[r];
      float* o = hp + ((size_t)b*NN + i0 + r) * 128 + dg;
      o[0] = sx*iz; o[1] = sy*iz; o[2] = sz*iz; o[3] = sw*iz;
    }
  }
}

// ---------------- final: out = f( relu(hp @ Wg2) @ Wd + bd ) ----------------
__global__ __launch_bounds__(128) void final_kernel(const float* __restrict__ hp,
    const float* __restrict__ Wg2, const float* __restrict__ Wd,
    const float* __restrict__ bd, float* __restrict__ out) {
  int row = blockIdx.x;
  int d = threadIdx.x;
  __shared__ float hrow[128];
  __shared__ float red[128];
  hrow[d] = hp[(size_t)row*128 + d];
  __syncthreads();
  float s = 0.f;
  #pragma unroll 8
  for (int k = 0; k < 128; ++k) s += hrow[k] * Wg2[(size_t)k*128 + d];
  s = s > 0.f ? s : 0.f;
  red[d] = s * Wd[d];
  __syncthreads();
  for (int st = 64; st > 0; st >>= 1) {
    if (d < st) red[d] += red[d + st];
    __syncthreads();
  }
  if (d == 0) {
    float o = red[0] + bd[0];
    out[row] = o / (1.f + fabsf(o)) - 1.f;
  }
}

extern "C" void kernel_launch(void* const* d_in, const int* in_sizes, int n_in,
                              void* d_out, int out_size, void* d_ws, size_t ws_size,
                              hipStream_t stream) {
  const float* x       = (const float*)d_in[0];
  const float* y       = (const float*)d_in[1];
  const int*   adj     = (const int*)  d_in[2];
  const float* W1_seg  = (const float*)d_in[3];
  const float* b1_seg  = (const float*)d_in[4];
  const float* g1_seg  = (const float*)d_in[5];
  const float* bt1_seg = (const float*)d_in[6];
  const float* W2_seg  = (const float*)d_in[7];
  const float* b2_seg  = (const float*)d_in[8];
  const float* g2_seg  = (const float*)d_in[9];
  const float* bt2_seg = (const float*)d_in[10];
  const float* W1_sp   = (const float*)d_in[11];
  const float* b1_sp   = (const float*)d_in[12];
  const float* g1_sp   = (const float*)d_in[13];
  const float* bt1_sp  = (const float*)d_in[14];
  const float* W2_sp   = (const float*)d_in[15];
  const float* b2_sp   = (const float*)d_in[16];
  const float* g2_sp   = (const float*)d_in[17];
  const float* bt2_sp  = (const float*)d_in[18];
  const float* Wg1     = (const float*)d_in[19];
  const float* Wg2     = (const float*)d_in[20];
  const float* a_vec   = (const float*)d_in[21];
  const float* Wd      = (const float*)d_in[22];
  const float* bd      = (const float*)d_in[23];
  float* out = (float*)d_out;

  float* ws    = (float*)d_ws;
  float* xs1   = ws;                 // 524288 floats (2,4096,64)
  float* xs2   = ws + 524288;        // 524288
  float* gbuf  = ws + 1048576;       // 1048576 (2,4096,128)
  float* hpbuf = ws + 2097152;       // 1048576
  float* sibuf = ws + 3145728;       // 8192
  float* sjbuf = ws + 3153920;       // 8192
  float* ys1   = ws + 3162112;       // 128
  float* cvec  = ws + 3162240;       // 256
  // total ~12.7 MB of d_ws

  gemm1_kernel<<<256, 256, 0, stream>>>(x, W1_seg, b1_seg, xs1);
  bn_elu_kernel<<<1024, 256, 0, stream>>>(xs1, xs1, g1_seg, bt1_seg, 262144);
  gemm2_kernel<<<128, 256, 0, stream>>>(xs1, W2_seg, b2_seg, xs2);
  bn_elu_kernel<<<1024, 256, 0, stream>>>(xs2, xs2, g2_seg, bt2_seg, 262144);
  sp1_kernel<<<128, 256, 0, stream>>>(y, W1_sp, b1_sp, ys1);
  sp2_kernel<<<1, 256, 0, stream>>>(ys1, g1_sp, bt1_sp, W2_sp, b2_sp, g2_sp, bt2_sp, Wg1, cvec);
  gemm3_kernel<<<128, 256, 0, stream>>>(xs2, Wg1, cvec, gbuf);
  sisj_kernel<<<2048, 256, 0, stream>>>(gbuf, a_vec, sibuf, sjbuf);
  att_kernel<<<dim3(1024, 2), 256, 0, stream>>>(adj, sibuf, sjbuf, gbuf, hpbuf);
  final_kernel<<<8192, 128, 0, stream>>>(hpbuf, Wg2, Wd, bd, out);
}

// Round 2
// 485.923 us; speedup vs baseline: 1.3797x; 1.3797x over previous
//
#include <hip/hip_runtime.h>
#include <hip/hip_bf16.h>
#include <cmath>

#define NN 4096

typedef __attribute__((ext_vector_type(8))) short bf16x8;
typedef __attribute__((ext_vector_type(4))) float f32x4;

static __device__ __forceinline__ short f2bf(float f) {
  unsigned u = __float_as_uint(f);
  unsigned r = (u + 0x7FFFu + ((u >> 16) & 1u)) >> 16;
  return (short)r;
}
static __device__ __forceinline__ float bf2f(short b) {
  return __uint_as_float(((unsigned)(unsigned short)b) << 16);
}

// ---------------- GEMM1: xs1 = x @ W1_seg + b1 ; X(8192,4096) W(4096,64) ----------------
__global__ __launch_bounds__(256) void gemm1_kernel(const float* __restrict__ X,
    const float* __restrict__ W, const float* __restrict__ bias, float* __restrict__ out) {
  __shared__ float As[64][34];
  __shared__ float Bs[64][64];
  int tid = threadIdx.x;
  int m0 = blockIdx.x * 32;
  int tx = tid & 15, ty = tid >> 4;
  float acc[2][4] = {};
  int lr = tid >> 3;
  int lk = (tid & 7) * 8;
  for (int k0 = 0; k0 < 4096; k0 += 64) {
    const float4* pa = (const float4*)(X + (size_t)(m0 + lr) * 4096 + k0 + lk);
    float4 v0 = pa[0], v1 = pa[1];
    As[lk+0][lr]=v0.x; As[lk+1][lr]=v0.y; As[lk+2][lr]=v0.z; As[lk+3][lr]=v0.w;
    As[lk+4][lr]=v1.x; As[lk+5][lr]=v1.y; As[lk+6][lr]=v1.z; As[lk+7][lr]=v1.w;
    #pragma unroll
    for (int e = 0; e < 16; ++e) {
      int idx = e * 256 + tid;
      Bs[idx >> 6][idx & 63] = W[(size_t)k0 * 64 + idx];
    }
    __syncthreads();
    #pragma unroll
    for (int kk = 0; kk < 64; ++kk) {
      float a0 = As[kk][ty*2+0], a1 = As[kk][ty*2+1];
      const float4 bv = *(const float4*)&Bs[kk][tx*4];
      acc[0][0] += a0*bv.x; acc[0][1] += a0*bv.y; acc[0][2] += a0*bv.z; acc[0][3] += a0*bv.w;
      acc[1][0] += a1*bv.x; acc[1][1] += a1*bv.y; acc[1][2] += a1*bv.z; acc[1][3] += a1*bv.w;
    }
    __syncthreads();
  }
  #pragma unroll
  for (int rr = 0; rr < 2; ++rr)
    #pragma unroll
    for (int cc = 0; cc < 4; ++cc)
      out[(size_t)(m0 + ty*2 + rr)*64 + tx*4 + cc] = acc[rr][cc] + bias[tx*4+cc];
}

// ---------------- batchnorm(B=2) + elu ----------------
__global__ void bn_elu_kernel(const float* __restrict__ src, float* __restrict__ dst,
    const float* __restrict__ gamma, const float* __restrict__ beta, int NH) {
  int idx = blockIdx.x * blockDim.x + threadIdx.x;
  if (idx >= NH) return;
  float a = src[idx], b = src[NH + idx];
  float d = 0.5f * (a - b);
  float inv = 1.0f / sqrtf(d*d + 1e-5f);
  float gm = gamma[idx], bt = beta[idx];
  float na =  d * inv * gm + bt;
  float nb = -d * inv * gm + bt;
  dst[idx]      = na > 0.f ? na : expm1f(na);
  dst[NH + idx] = nb > 0.f ? nb : expm1f(nb);
}

// ---------------- GEMM2: (8192,64)@(64,64)+bias ----------------
__global__ __launch_bounds__(256) void gemm2_kernel(const float* __restrict__ X,
    const float* __restrict__ W, const float* __restrict__ bias, float* __restrict__ out) {
  __shared__ float As[64][65];
  __shared__ float Bs[64][64];
  int tid = threadIdx.x;
  int m0 = blockIdx.x * 64;
  #pragma unroll
  for (int e = 0; e < 16; ++e) {
    int idx = e*256 + tid;
    int r = idx >> 6, c = idx & 63;
    As[r][c] = X[(size_t)m0*64 + idx];
    Bs[r][c] = W[idx];
  }
  __syncthreads();
  int tx = tid & 15, ty = tid >> 4;
  float acc[4][4] = {};
  #pragma unroll 8
  for (int kk = 0; kk < 64; ++kk) {
    float a0 = As[ty*4+0][kk], a1 = As[ty*4+1][kk], a2 = As[ty*4+2][kk], a3 = As[ty*4+3][kk];
    const float4 bv = *(const float4*)&Bs[kk][tx*4];
    acc[0][0]+=a0*bv.x; acc[0][1]+=a0*bv.y; acc[0][2]+=a0*bv.z; acc[0][3]+=a0*bv.w;
    acc[1][0]+=a1*bv.x; acc[1][1]+=a1*bv.y; acc[1][2]+=a1*bv.z; acc[1][3]+=a1*bv.w;
    acc[2][0]+=a2*bv.x; acc[2][1]+=a2*bv.y; acc[2][2]+=a2*bv.z; acc[2][3]+=a2*bv.w;
    acc[3][0]+=a3*bv.x; acc[3][1]+=a3*bv.y; acc[3][2]+=a3*bv.z; acc[3][3]+=a3*bv.w;
  }
  #pragma unroll
  for (int rr = 0; rr < 4; ++rr)
    #pragma unroll
    for (int cc = 0; cc < 4; ++cc)
      out[(size_t)(m0 + ty*4 + rr)*64 + tx*4 + cc] = acc[rr][cc] + bias[tx*4+cc];
}

// ---------------- GEMM3: g = xs @ Wg1[:64,:] + cvec[b] ----------------
__global__ __launch_bounds__(256) void gemm3_kernel(const float* __restrict__ X,
    const float* __restrict__ Wg1, const float* __restrict__ cvec, float* __restrict__ out) {
  __shared__ float As[64][65];
  __shared__ float Bs[64][128];
  int tid = threadIdx.x;
  int m0 = blockIdx.x * 64;
  int b = m0 >> 12;
  #pragma unroll
  for (int e = 0; e < 16; ++e) {
    int idx = e*256 + tid;
    As[idx>>6][idx&63] = X[(size_t)m0*64 + idx];
  }
  #pragma unroll
  for (int e = 0; e < 32; ++e) {
    int idx = e*256 + tid;
    Bs[idx>>7][idx&127] = Wg1[idx];
  }
  __syncthreads();
  int tx = tid & 15, ty = tid >> 4;
  float acc0[4][4] = {};
  float acc1[4][4] = {};
  #pragma unroll 4
  for (int kk = 0; kk < 64; ++kk) {
    float a[4];
    #pragma unroll
    for (int rr = 0; rr < 4; ++rr) a[rr] = As[ty*4+rr][kk];
    const float4 b0 = *(const float4*)&Bs[kk][tx*4];
    const float4 b1 = *(const float4*)&Bs[kk][64 + tx*4];
    #pragma unroll
    for (int rr = 0; rr < 4; ++rr) {
      acc0[rr][0]+=a[rr]*b0.x; acc0[rr][1]+=a[rr]*b0.y; acc0[rr][2]+=a[rr]*b0.z; acc0[rr][3]+=a[rr]*b0.w;
      acc1[rr][0]+=a[rr]*b1.x; acc1[rr][1]+=a[rr]*b1.y; acc1[rr][2]+=a[rr]*b1.z; acc1[rr][3]+=a[rr]*b1.w;
    }
  }
  #pragma unroll
  for (int rr = 0; rr < 4; ++rr) {
    size_t rb = (size_t)(m0 + ty*4 + rr) * 128;
    #pragma unroll
    for (int cc = 0; cc < 4; ++cc) {
      int c0 = tx*4 + cc, c1 = 64 + tx*4 + cc;
      out[rb + c0] = acc0[rr][cc] + cvec[b*128 + c0];
      out[rb + c1] = acc1[rr][cc] + cvec[b*128 + c1];
    }
  }
}

// ---------------- transpose g (fp32 [2][4096][128]) -> gT (bf16 [2][128][4096]) ----------------
__global__ __launch_bounds__(256) void transpose_g_kernel(const float* __restrict__ g,
    short* __restrict__ gT) {
  int b = blockIdx.y;
  int j0 = blockIdx.x * 64;
  __shared__ short t[128][72];          // pitch 72 shorts = 144 B (16B-aligned rows)
  int tid = threadIdx.x;
  int jj = tid >> 5;                    // 0..7
  int d0 = (tid & 31) * 4;
  #pragma unroll
  for (int r = 0; r < 8; ++r) {
    int j = jj + r * 8;
    float4 v = *(const float4*)(g + ((size_t)b*NN + j0 + j)*128 + d0);
    t[d0+0][j] = f2bf(v.x); t[d0+1][j] = f2bf(v.y);
    t[d0+2][j] = f2bf(v.z); t[d0+3][j] = f2bf(v.w);
  }
  __syncthreads();
  int d = tid >> 1, jh = (tid & 1) * 32;
  #pragma unroll
  for (int q = 0; q < 4; ++q) {
    bf16x8 v = *(const bf16x8*)&t[d][jh + q*8];
    *(bf16x8*)(gT + ((size_t)b << 19) + (size_t)d*NN + j0 + jh + q*8) = v;
  }
}

// ---------------- si/sj ----------------
__global__ __launch_bounds__(256) void sisj_kernel(const float* __restrict__ g,
    const float* __restrict__ a_vec, float* __restrict__ si, float* __restrict__ sj) {
  int wave = threadIdx.x >> 6, lane = threadIdx.x & 63;
  int row = blockIdx.x * 4 + wave;
  const float* gr = g + (size_t)row * 128;
  float g0 = gr[lane], g1 = gr[lane + 64];
  float v1 = g0 * a_vec[lane]       + g1 * a_vec[lane + 64];
  float v2 = g0 * a_vec[128 + lane] + g1 * a_vec[192 + lane];
  #pragma unroll
  for (int off = 32; off > 0; off >>= 1) {
    v1 += __shfl_down(v1, off);
    v2 += __shfl_down(v2, off);
  }
  if (lane == 0) { si[row] = v1; sj[row] = v2; }
}

// ---------------- sp branch part 1 ----------------
__global__ __launch_bounds__(256) void sp1_kernel(const float* __restrict__ y,
    const float* __restrict__ W, const float* __restrict__ bias, float* __restrict__ ys1) {
  int b = blockIdx.x >> 6, h = blockIdx.x & 63;
  float s = 0.f;
  for (int k = threadIdx.x; k < NN; k += 256)
    s += y[b*NN + k] * W[(size_t)k*64 + h];
  __shared__ float red[256];
  red[threadIdx.x] = s; __syncthreads();
  for (int st = 128; st > 0; st >>= 1) {
    if (threadIdx.x < st) red[threadIdx.x] += red[threadIdx.x + st];
    __syncthreads();
  }
  if (threadIdx.x == 0) ys1[blockIdx.x] = red[0] + bias[h];
}

// ---------------- sp branch remainder + cvec ----------------
__global__ __launch_bounds__(256) void sp2_kernel(const float* __restrict__ ys1,
    const float* __restrict__ g1, const float* __restrict__ bt1,
    const float* __restrict__ W2, const float* __restrict__ b2,
    const float* __restrict__ g2, const float* __restrict__ bt2,
    const float* __restrict__ Wg1, float* __restrict__ cvec) {
  __shared__ float e1[2][64];
  __shared__ float y2[2][64];
  __shared__ float e2[2][64];
  int tid = threadIdx.x;
  if (tid < 64) {
    float a = ys1[tid], b = ys1[64 + tid];
    float d = 0.5f * (a - b);
    float inv = 1.0f / sqrtf(d*d + 1e-5f);
    float na =  d*inv*g1[tid] + bt1[tid];
    float nb = -d*inv*g1[tid] + bt1[tid];
    e1[0][tid] = na > 0.f ? na : expm1f(na);
    e1[1][tid] = nb > 0.f ? nb : expm1f(nb);
  }
  __syncthreads();
  if (tid < 128) {
    int b = tid >> 6, h = tid & 63;
    float s = b2[h];
    for (int k = 0; k < 64; ++k) s += e1[b][k] * W2[k*64 + h];
    y2[b][h] = s;
  }
  __syncthreads();
  if (tid < 64) {
    float a = y2[0][tid], b = y2[1][tid];
    float d = 0.5f * (a - b);
    float inv = 1.0f / sqrtf(d*d + 1e-5f);
    float na =  d*inv*g2[tid] + bt2[tid];
    float nb = -d*inv*g2[tid] + bt2[tid];
    e2[0][tid] = na > 0.f ? na : expm1f(na);
    e2[1][tid] = nb > 0.f ? nb : expm1f(nb);
  }
  __syncthreads();
  {
    int b = tid >> 7, o = tid & 127;
    float s = 0.f;
    for (int h = 0; h < 64; ++h) s += e2[b][h] * Wg1[(64 + h)*128 + o];
    cvec[tid] = s;
  }
}

// ---------------- attention via MFMA ----------------
// Per block: BI=16 rows, full d=128. 4 waves, wave w owns d in [32w,32w+32).
// j-loop in tiles of BJ=128: generate w-tile bf16 in LDS (A operand),
// B operand = gT[b][d][j] read as 8 contiguous j per lane (16B, L2-hot).
// Z accumulated per-thread in fp32 from the *rounded* bf16 weights.
__global__ __launch_bounds__(256) void att_mfma_kernel(const int* __restrict__ adj,
    const float* __restrict__ si, const float* __restrict__ sj,
    const short* __restrict__ gT, float* __restrict__ hp) {
  __shared__ short w_lds[16 * 136];     // pitch 136 shorts = 272 B; A-read = 2-way bank alias (free)
  __shared__ float zinv_s[16];
  const int b = blockIdx.y;
  const int i0 = blockIdx.x * 16;
  const int tid = threadIdx.x;

  // W-phase identity (all 256 threads): row 0..15, 8 j's each
  const int row = tid >> 4;
  const int jb = (tid & 15) * 8;
  const float siv = si[(size_t)b*NN + i0 + row];
  const int* arow = adj + (size_t)(i0 + row) * NN + jb;
  const float* sjrow = sj + (size_t)b * NN + jb;
  short* wrow = w_lds + row * 136 + jb;
  float zacc = 0.f;

  // M-phase identity (per wave)
  const int l = tid & 63, wq = tid >> 6;
  const int col = l & 15;               // A-row / B-col / C-col
  const int kg = l >> 4;                // k-group 0..3
  const short* apA = w_lds + col * 136 + kg * 8;
  const short* gb0 = gT + ((size_t)b << 19) + (size_t)(wq * 32 + col) * NN + kg * 8;
  const short* gb1 = gb0 + (size_t)16 * NN;
  f32x4 acc0 = {0.f, 0.f, 0.f, 0.f};
  f32x4 acc1 = {0.f, 0.f, 0.f, 0.f};

  for (int j0 = 0; j0 < NN; j0 += 128) {
    int4 a0 = *(const int4*)(arow + j0);
    int4 a1 = *(const int4*)(arow + j0 + 4);
    float4 s0 = *(const float4*)(sjrow + j0);
    float4 s1 = *(const float4*)(sjrow + j0 + 4);
    int av[8] = {a0.x, a0.y, a0.z, a0.w, a1.x, a1.y, a1.z, a1.w};
    float sv[8] = {s0.x, s0.y, s0.z, s0.w, s1.x, s1.y, s1.z, s1.w};
    bf16x8 wv;
    #pragma unroll
    for (int e = 0; e < 8; ++e) {
      float ev = siv + sv[e];
      ev = ev >= 0.f ? ev : 0.2f * ev;
      float wf = __expf(ev);
      short wb = (av[e] != 0) ? f2bf(wf) : (short)0;
      wv[e] = wb;
      zacc += bf2f(wb);
    }
    *(bf16x8*)wrow = wv;
    __syncthreads();

    #pragma unroll
    for (int kh = 0; kh < 4; ++kh) {
      bf16x8 af = *(const bf16x8*)(apA + kh * 32);
      bf16x8 bf0 = *(const bf16x8*)(gb0 + j0 + kh * 32);
      bf16x8 bf1 = *(const bf16x8*)(gb1 + j0 + kh * 32);
      acc0 = __builtin_amdgcn_mfma_f32_16x16x32_bf16(af, bf0, acc0, 0, 0, 0);
      acc1 = __builtin_amdgcn_mfma_f32_16x16x32_bf16(af, bf1, acc1, 0, 0, 0);
    }
    __syncthreads();
  }

  // Z reduce: 16 partials per row live in one wave (lanes sharing l>>4)
  float z = zacc;
  z += __shfl_xor(z, 1); z += __shfl_xor(z, 2);
  z += __shfl_xor(z, 4); z += __shfl_xor(z, 8);
  if ((tid & 15) == 0) zinv_s[row] = z > 0.f ? 1.f / z : 0.f;
  __syncthreads();

  // C layout (m89-verified): col = l&15, row = (l>>4)*4 + e
  #pragma unroll
  for (int e = 0; e < 4; ++e) {
    int r = kg * 4 + e;
    float iz = zinv_s[r];
    float* o = hp + ((size_t)b*NN + i0 + r) * 128;
    o[wq * 32 + col]      = acc0[e] * iz;
    o[wq * 32 + 16 + col] = acc1[e] * iz;
  }
}

// ---------------- final: out = f( relu(hp @ Wg2) @ Wd + bd ) ----------------
__global__ __launch_bounds__(128) void final_kernel(const float* __restrict__ hp,
    const float* __restrict__ Wg2, const float* __restrict__ Wd,
    const float* __restrict__ bd, float* __restrict__ out) {
  int row = blockIdx.x;
  int d = threadIdx.x;
  __shared__ float hrow[128];
  __shared__ float red[128];
  hrow[d] = hp[(size_t)row*128 + d];
  __syncthreads();
  float s = 0.f;
  #pragma unroll 8
  for (int k = 0; k < 128; ++k) s += hrow[k] * Wg2[(size_t)k*128 + d];
  s = s > 0.f ? s : 0.f;
  red[d] = s * Wd[d];
  __syncthreads();
  for (int st = 64; st > 0; st >>= 1) {
    if (d < st) red[d] += red[d + st];
    __syncthreads();
  }
  if (d == 0) {
    float o = red[0] + bd[0];
    out[row] = o / (1.f + fabsf(o)) - 1.f;
  }
}

extern "C" void kernel_launch(void* const* d_in, const int* in_sizes, int n_in,
                              void* d_out, int out_size, void* d_ws, size_t ws_size,
                              hipStream_t stream) {
  const float* x       = (const float*)d_in[0];
  const float* y       = (const float*)d_in[1];
  const int*   adj     = (const int*)  d_in[2];
  const float* W1_seg  = (const float*)d_in[3];
  const float* b1_seg  = (const float*)d_in[4];
  const float* g1_seg  = (const float*)d_in[5];
  const float* bt1_seg = (const float*)d_in[6];
  const float* W2_seg  = (const float*)d_in[7];
  const float* b2_seg  = (const float*)d_in[8];
  const float* g2_seg  = (const float*)d_in[9];
  const float* bt2_seg = (const float*)d_in[10];
  const float* W1_sp   = (const float*)d_in[11];
  const float* b1_sp   = (const float*)d_in[12];
  const float* g1_sp   = (const float*)d_in[13];
  const float* bt1_sp  = (const float*)d_in[14];
  const float* W2_sp   = (const float*)d_in[15];
  const float* b2_sp   = (const float*)d_in[16];
  const float* g2_sp   = (const float*)d_in[17];
  const float* bt2_sp  = (const float*)d_in[18];
  const float* Wg1     = (const float*)d_in[19];
  const float* Wg2     = (const float*)d_in[20];
  const float* a_vec   = (const float*)d_in[21];
  const float* Wd      = (const float*)d_in[22];
  const float* bd      = (const float*)d_in[23];
  float* out = (float*)d_out;

  float* ws    = (float*)d_ws;
  float* xs1   = ws;                 // 524288 floats
  float* xs2   = ws + 524288;        // 524288
  float* gbuf  = ws + 1048576;       // 1048576
  float* hpbuf = ws + 2097152;       // 1048576
  float* sibuf = ws + 3145728;       // 8192
  float* sjbuf = ws + 3153920;       // 8192
  float* ys1   = ws + 3162112;       // 128
  float* cvec  = ws + 3162240;       // 256
  short* gTbuf = (short*)(ws + 3162496); // 2*128*4096 bf16 = 2 MB

  gemm1_kernel<<<256, 256, 0, stream>>>(x, W1_seg, b1_seg, xs1);
  bn_elu_kernel<<<1024, 256, 0, stream>>>(xs1, xs1, g1_seg, bt1_seg, 262144);
  gemm2_kernel<<<128, 256, 0, stream>>>(xs1, W2_seg, b2_seg, xs2);
  bn_elu_kernel<<<1024, 256, 0, stream>>>(xs2, xs2, g2_seg, bt2_seg, 262144);
  sp1_kernel<<<128, 256, 0, stream>>>(y, W1_sp, b1_sp, ys1);
  sp2_kernel<<<1, 256, 0, stream>>>(ys1, g1_sp, bt1_sp, W2_sp, b2_sp, g2_sp, bt2_sp, Wg1, cvec);
  gemm3_kernel<<<128, 256, 0, stream>>>(xs2, Wg1, cvec, gbuf);
  transpose_g_kernel<<<dim3(64, 2), 256, 0, stream>>>(gbuf, gTbuf);
  sisj_kernel<<<2048, 256, 0, stream>>>(gbuf, a_vec, sibuf, sjbuf);
  att_mfma_kernel<<<dim3(256, 2), 256, 0, stream>>>(adj, sibuf, sjbuf, gTbuf, hpbuf);
  final_kernel<<<8192, 128, 0, stream>>>(hpbuf, Wg2, Wd, bd, out);
}

// Round 3
// 403.470 us; speedup vs baseline: 1.6617x; 1.2044x over previous
//
#include <hip/hip_runtime.h>
#include <hip/hip_bf16.h>
#include <cmath>

#define NN 4096

typedef __attribute__((ext_vector_type(8))) short bf16x8;
typedef __attribute__((ext_vector_type(4))) float f32x4;

static __device__ __forceinline__ short f2bf(float f) {
  unsigned u = __float_as_uint(f);
  unsigned r = (u + 0x7FFFu + ((u >> 16) & 1u)) >> 16;
  return (short)r;
}
static __device__ __forceinline__ float bf2f(short b) {
  return __uint_as_float(((unsigned)(unsigned short)b) << 16);
}

// ---------------- prep: W1_seg fp32 [4096][64] -> W1T bf16 [64][4096] ----------------
__global__ __launch_bounds__(256) void prep_w1_kernel(const float* __restrict__ W,
    short* __restrict__ WT) {
  __shared__ short t[64][72];
  int k0 = blockIdx.x * 64;
  int tid = threadIdx.x;
  #pragma unroll
  for (int e = 0; e < 4; ++e) {
    int idx = e * 1024 + tid * 4;          // 64 rows(k) x 64 cols
    int r = idx >> 6, c = idx & 63;
    float4 v = *(const float4*)(W + (size_t)(k0 + r) * 64 + c);
    t[c + 0][r] = f2bf(v.x); t[c + 1][r] = f2bf(v.y);
    t[c + 2][r] = f2bf(v.z); t[c + 3][r] = f2bf(v.w);
  }
  __syncthreads();
  int c = tid >> 2, kq = (tid & 3) * 16;
  #pragma unroll
  for (int q = 0; q < 2; ++q) {
    bf16x8 v = *(const bf16x8*)&t[c][kq + q * 8];
    *(bf16x8*)(WT + (size_t)c * 4096 + k0 + kq + q * 8) = v;
  }
}

// ---------------- GEMM1 via MFMA: xs1 = x @ W1_seg + b1 ----------------
// Block: 16 rows (M), 64 cols (N) = 4 waves x one 16x16 tile. K-step 128.
// A staged fp32->bf16 in LDS; B from pre-transposed bf16 W1T (L2-hot).
__global__ __launch_bounds__(256) void gemm1_mfma_kernel(const float* __restrict__ X,
    const short* __restrict__ WT, const float* __restrict__ bias, float* __restrict__ out) {
  __shared__ short As[16 * 136];
  int tid = threadIdx.x;
  int m0 = blockIdx.x * 16;
  int lr = tid >> 4, lc = (tid & 15) * 8;
  const float* xp = X + (size_t)(m0 + lr) * 4096 + lc;
  short* wp = As + lr * 136 + lc;
  int l = tid & 63, wq = tid >> 6;
  int col = l & 15, kg = l >> 4;
  const short* bp = WT + (size_t)(wq * 16 + col) * 4096 + kg * 8;
  const short* ap = As + col * 136 + kg * 8;
  f32x4 acc = {0.f, 0.f, 0.f, 0.f};
  for (int k0 = 0; k0 < 4096; k0 += 128) {
    float4 v0 = *(const float4*)(xp + k0);
    float4 v1 = *(const float4*)(xp + k0 + 4);
    bf16x8 wv;
    wv[0] = f2bf(v0.x); wv[1] = f2bf(v0.y); wv[2] = f2bf(v0.z); wv[3] = f2bf(v0.w);
    wv[4] = f2bf(v1.x); wv[5] = f2bf(v1.y); wv[6] = f2bf(v1.z); wv[7] = f2bf(v1.w);
    *(bf16x8*)wp = wv;
    __syncthreads();
    #pragma unroll
    for (int ks = 0; ks < 4; ++ks) {
      bf16x8 af = *(const bf16x8*)(ap + ks * 32);
      bf16x8 bf = *(const bf16x8*)(bp + k0 + ks * 32);
      acc = __builtin_amdgcn_mfma_f32_16x16x32_bf16(af, bf, acc, 0, 0, 0);
    }
    __syncthreads();
  }
  #pragma unroll
  for (int e = 0; e < 4; ++e) {
    int r = kg * 4 + e;
    out[(size_t)(m0 + r) * 64 + wq * 16 + col] = acc[e] + bias[wq * 16 + col];
  }
}

// ---------------- batchnorm(B=2) + elu ----------------
__global__ void bn_elu_kernel(const float* __restrict__ src, float* __restrict__ dst,
    const float* __restrict__ gamma, const float* __restrict__ beta, int NH) {
  int idx = blockIdx.x * blockDim.x + threadIdx.x;
  if (idx >= NH) return;
  float a = src[idx], b = src[NH + idx];
  float d = 0.5f * (a - b);
  float inv = 1.0f / sqrtf(d*d + 1e-5f);
  float gm = gamma[idx], bt = beta[idx];
  float na =  d * inv * gm + bt;
  float nb = -d * inv * gm + bt;
  dst[idx]      = na > 0.f ? na : expm1f(na);
  dst[NH + idx] = nb > 0.f ? nb : expm1f(nb);
}

// ---------------- GEMM2: (8192,64)@(64,64)+bias ----------------
__global__ __launch_bounds__(256) void gemm2_kernel(const float* __restrict__ X,
    const float* __restrict__ W, const float* __restrict__ bias, float* __restrict__ out) {
  __shared__ float As[64][65];
  __shared__ float Bs[64][64];
  int tid = threadIdx.x;
  int m0 = blockIdx.x * 64;
  #pragma unroll
  for (int e = 0; e < 16; ++e) {
    int idx = e*256 + tid;
    int r = idx >> 6, c = idx & 63;
    As[r][c] = X[(size_t)m0*64 + idx];
    Bs[r][c] = W[idx];
  }
  __syncthreads();
  int tx = tid & 15, ty = tid >> 4;
  float acc[4][4] = {};
  #pragma unroll 8
  for (int kk = 0; kk < 64; ++kk) {
    float a0 = As[ty*4+0][kk], a1 = As[ty*4+1][kk], a2 = As[ty*4+2][kk], a3 = As[ty*4+3][kk];
    const float4 bv = *(const float4*)&Bs[kk][tx*4];
    acc[0][0]+=a0*bv.x; acc[0][1]+=a0*bv.y; acc[0][2]+=a0*bv.z; acc[0][3]+=a0*bv.w;
    acc[1][0]+=a1*bv.x; acc[1][1]+=a1*bv.y; acc[1][2]+=a1*bv.z; acc[1][3]+=a1*bv.w;
    acc[2][0]+=a2*bv.x; acc[2][1]+=a2*bv.y; acc[2][2]+=a2*bv.z; acc[2][3]+=a2*bv.w;
    acc[3][0]+=a3*bv.x; acc[3][1]+=a3*bv.y; acc[3][2]+=a3*bv.z; acc[3][3]+=a3*bv.w;
  }
  #pragma unroll
  for (int rr = 0; rr < 4; ++rr)
    #pragma unroll
    for (int cc = 0; cc < 4; ++cc)
      out[(size_t)(m0 + ty*4 + rr)*64 + tx*4 + cc] = acc[rr][cc] + bias[tx*4+cc];
}

// ---------------- GEMM3: g = xs @ Wg1[:64,:] + cvec[b] ----------------
__global__ __launch_bounds__(256) void gemm3_kernel(const float* __restrict__ X,
    const float* __restrict__ Wg1, const float* __restrict__ cvec, float* __restrict__ out) {
  __shared__ float As[64][65];
  __shared__ float Bs[64][128];
  int tid = threadIdx.x;
  int m0 = blockIdx.x * 64;
  int b = m0 >> 12;
  #pragma unroll
  for (int e = 0; e < 16; ++e) {
    int idx = e*256 + tid;
    As[idx>>6][idx&63] = X[(size_t)m0*64 + idx];
  }
  #pragma unroll
  for (int e = 0; e < 32; ++e) {
    int idx = e*256 + tid;
    Bs[idx>>7][idx&127] = Wg1[idx];
  }
  __syncthreads();
  int tx = tid & 15, ty = tid >> 4;
  float acc0[4][4] = {};
  float acc1[4][4] = {};
  #pragma unroll 4
  for (int kk = 0; kk < 64; ++kk) {
    float a[4];
    #pragma unroll
    for (int rr = 0; rr < 4; ++rr) a[rr] = As[ty*4+rr][kk];
    const float4 b0 = *(const float4*)&Bs[kk][tx*4];
    const float4 b1 = *(const float4*)&Bs[kk][64 + tx*4];
    #pragma unroll
    for (int rr = 0; rr < 4; ++rr) {
      acc0[rr][0]+=a[rr]*b0.x; acc0[rr][1]+=a[rr]*b0.y; acc0[rr][2]+=a[rr]*b0.z; acc0[rr][3]+=a[rr]*b0.w;
      acc1[rr][0]+=a[rr]*b1.x; acc1[rr][1]+=a[rr]*b1.y; acc1[rr][2]+=a[rr]*b1.z; acc1[rr][3]+=a[rr]*b1.w;
    }
  }
  #pragma unroll
  for (int rr = 0; rr < 4; ++rr) {
    size_t rb = (size_t)(m0 + ty*4 + rr) * 128;
    #pragma unroll
    for (int cc = 0; cc < 4; ++cc) {
      int c0 = tx*4 + cc, c1 = 64 + tx*4 + cc;
      out[rb + c0] = acc0[rr][cc] + cvec[b*128 + c0];
      out[rb + c1] = acc1[rr][cc] + cvec[b*128 + c1];
    }
  }
}

// ---------------- transpose g (fp32 [2][4096][128]) -> gT (bf16 [2][128][4096]) ----------------
__global__ __launch_bounds__(256) void transpose_g_kernel(const float* __restrict__ g,
    short* __restrict__ gT) {
  int b = blockIdx.y;
  int j0 = blockIdx.x * 64;
  __shared__ short t[128][72];
  int tid = threadIdx.x;
  int jj = tid >> 5;
  int d0 = (tid & 31) * 4;
  #pragma unroll
  for (int r = 0; r < 8; ++r) {
    int j = jj + r * 8;
    float4 v = *(const float4*)(g + ((size_t)b*NN + j0 + j)*128 + d0);
    t[d0+0][j] = f2bf(v.x); t[d0+1][j] = f2bf(v.y);
    t[d0+2][j] = f2bf(v.z); t[d0+3][j] = f2bf(v.w);
  }
  __syncthreads();
  int d = tid >> 1, jh = (tid & 1) * 32;
  #pragma unroll
  for (int q = 0; q < 4; ++q) {
    bf16x8 v = *(const bf16x8*)&t[d][jh + q*8];
    *(bf16x8*)(gT + ((size_t)b << 19) + (size_t)d*NN + j0 + jh + q*8) = v;
  }
}

// ---------------- si/sj ----------------
__global__ __launch_bounds__(256) void sisj_kernel(const float* __restrict__ g,
    const float* __restrict__ a_vec, float* __restrict__ si, float* __restrict__ sj) {
  int wave = threadIdx.x >> 6, lane = threadIdx.x & 63;
  int row = blockIdx.x * 4 + wave;
  const float* gr = g + (size_t)row * 128;
  float g0 = gr[lane], g1 = gr[lane + 64];
  float v1 = g0 * a_vec[lane]       + g1 * a_vec[lane + 64];
  float v2 = g0 * a_vec[128 + lane] + g1 * a_vec[192 + lane];
  #pragma unroll
  for (int off = 32; off > 0; off >>= 1) {
    v1 += __shfl_down(v1, off);
    v2 += __shfl_down(v2, off);
  }
  if (lane == 0) { si[row] = v1; sj[row] = v2; }
}

// ---------------- sp branch part 1 ----------------
__global__ __launch_bounds__(256) void sp1_kernel(const float* __restrict__ y,
    const float* __restrict__ W, const float* __restrict__ bias, float* __restrict__ ys1) {
  int b = blockIdx.x >> 6, h = blockIdx.x & 63;
  float s = 0.f;
  for (int k = threadIdx.x; k < NN; k += 256)
    s += y[b*NN + k] * W[(size_t)k*64 + h];
  __shared__ float red[256];
  red[threadIdx.x] = s; __syncthreads();
  for (int st = 128; st > 0; st >>= 1) {
    if (threadIdx.x < st) red[threadIdx.x] += red[threadIdx.x + st];
    __syncthreads();
  }
  if (threadIdx.x == 0) ys1[blockIdx.x] = red[0] + bias[h];
}

// ---------------- sp branch remainder + cvec ----------------
__global__ __launch_bounds__(256) void sp2_kernel(const float* __restrict__ ys1,
    const float* __restrict__ g1, const float* __restrict__ bt1,
    const float* __restrict__ W2, const float* __restrict__ b2,
    const float* __restrict__ g2, const float* __restrict__ bt2,
    const float* __restrict__ Wg1, float* __restrict__ cvec) {
  __shared__ float e1[2][64];
  __shared__ float y2[2][64];
  __shared__ float e2[2][64];
  int tid = threadIdx.x;
  if (tid < 64) {
    float a = ys1[tid], b = ys1[64 + tid];
    float d = 0.5f * (a - b);
    float inv = 1.0f / sqrtf(d*d + 1e-5f);
    float na =  d*inv*g1[tid] + bt1[tid];
    float nb = -d*inv*g1[tid] + bt1[tid];
    e1[0][tid] = na > 0.f ? na : expm1f(na);
    e1[1][tid] = nb > 0.f ? nb : expm1f(nb);
  }
  __syncthreads();
  if (tid < 128) {
    int b = tid >> 6, h = tid & 63;
    float s = b2[h];
    for (int k = 0; k < 64; ++k) s += e1[b][k] * W2[k*64 + h];
    y2[b][h] = s;
  }
  __syncthreads();
  if (tid < 64) {
    float a = y2[0][tid], b = y2[1][tid];
    float d = 0.5f * (a - b);
    float inv = 1.0f / sqrtf(d*d + 1e-5f);
    float na =  d*inv*g2[tid] + bt2[tid];
    float nb = -d*inv*g2[tid] + bt2[tid];
    e2[0][tid] = na > 0.f ? na : expm1f(na);
    e2[1][tid] = nb > 0.f ? nb : expm1f(nb);
  }
  __syncthreads();
  {
    int b = tid >> 7, o = tid & 127;
    float s = 0.f;
    for (int h = 0; h < 64; ++h) s += e2[b][h] * Wg1[(64 + h)*128 + o];
    cvec[tid] = s;
  }
}

// ---------------- attention via MFMA ----------------
__global__ __launch_bounds__(256) void att_mfma_kernel(const int* __restrict__ adj,
    const float* __restrict__ si, const float* __restrict__ sj,
    const short* __restrict__ gT, float* __restrict__ hp) {
  __shared__ short w_lds[16 * 136];
  __shared__ float zinv_s[16];
  const int b = blockIdx.y;
  const int i0 = blockIdx.x * 16;
  const int tid = threadIdx.x;

  const int row = tid >> 4;
  const int jb = (tid & 15) * 8;
  const float siv = si[(size_t)b*NN + i0 + row];
  const int* arow = adj + (size_t)(i0 + row) * NN + jb;
  const float* sjrow = sj + (size_t)b * NN + jb;
  short* wrow = w_lds + row * 136 + jb;
  float zacc = 0.f;

  const int l = tid & 63, wq = tid >> 6;
  const int col = l & 15;
  const int kg = l >> 4;
  const short* apA = w_lds + col * 136 + kg * 8;
  const short* gb0 = gT + ((size_t)b << 19) + (size_t)(wq * 32 + col) * NN + kg * 8;
  const short* gb1 = gb0 + (size_t)16 * NN;
  f32x4 acc0 = {0.f, 0.f, 0.f, 0.f};
  f32x4 acc1 = {0.f, 0.f, 0.f, 0.f};

  for (int j0 = 0; j0 < NN; j0 += 128) {
    int4 a0 = *(const int4*)(arow + j0);
    int4 a1 = *(const int4*)(arow + j0 + 4);
    float4 s0 = *(const float4*)(sjrow + j0);
    float4 s1 = *(const float4*)(sjrow + j0 + 4);
    int av[8] = {a0.x, a0.y, a0.z, a0.w, a1.x, a1.y, a1.z, a1.w};
    float sv[8] = {s0.x, s0.y, s0.z, s0.w, s1.x, s1.y, s1.z, s1.w};
    bf16x8 wv;
    #pragma unroll
    for (int e = 0; e < 8; ++e) {
      float ev = siv + sv[e];
      ev = ev >= 0.f ? ev : 0.2f * ev;
      float wf = __expf(ev);
      short wb = (av[e] != 0) ? f2bf(wf) : (short)0;
      wv[e] = wb;
      zacc += bf2f(wb);
    }
    *(bf16x8*)wrow = wv;
    __syncthreads();

    #pragma unroll
    for (int kh = 0; kh < 4; ++kh) {
      bf16x8 af = *(const bf16x8*)(apA + kh * 32);
      bf16x8 bf0 = *(const bf16x8*)(gb0 + j0 + kh * 32);
      bf16x8 bf1 = *(const bf16x8*)(gb1 + j0 + kh * 32);
      acc0 = __builtin_amdgcn_mfma_f32_16x16x32_bf16(af, bf0, acc0, 0, 0, 0);
      acc1 = __builtin_amdgcn_mfma_f32_16x16x32_bf16(af, bf1, acc1, 0, 0, 0);
    }
    __syncthreads();
  }

  float z = zacc;
  z += __shfl_xor(z, 1); z += __shfl_xor(z, 2);
  z += __shfl_xor(z, 4); z += __shfl_xor(z, 8);
  if ((tid & 15) == 0) zinv_s[row] = z > 0.f ? 1.f / z : 0.f;
  __syncthreads();

  #pragma unroll
  for (int e = 0; e < 4; ++e) {
    int r = kg * 4 + e;
    float iz = zinv_s[r];
    float* o = hp + ((size_t)b*NN + i0 + r) * 128;
    o[wq * 32 + col]      = acc0[e] * iz;
    o[wq * 32 + 16 + col] = acc1[e] * iz;
  }
}

// ---------------- final ----------------
__global__ __launch_bounds__(128) void final_kernel(const float* __restrict__ hp,
    const float* __restrict__ Wg2, const float* __restrict__ Wd,
    const float* __restrict__ bd, float* __restrict__ out) {
  int row = blockIdx.x;
  int d = threadIdx.x;
  __shared__ float hrow[128];
  __shared__ float red[128];
  hrow[d] = hp[(size_t)row*128 + d];
  __syncthreads();
  float s = 0.f;
  #pragma unroll 8
  for (int k = 0; k < 128; ++k) s += hrow[k] * Wg2[(size_t)k*128 + d];
  s = s > 0.f ? s : 0.f;
  red[d] = s * Wd[d];
  __syncthreads();
  for (int st = 64; st > 0; st >>= 1) {
    if (d < st) red[d] += red[d + st];
    __syncthreads();
  }
  if (d == 0) {
    float o = red[0] + bd[0];
    out[row] = o / (1.f + fabsf(o)) - 1.f;
  }
}

extern "C" void kernel_launch(void* const* d_in, const int* in_sizes, int n_in,
                              void* d_out, int out_size, void* d_ws, size_t ws_size,
                              hipStream_t stream) {
  const float* x       = (const float*)d_in[0];
  const float* y       = (const float*)d_in[1];
  const int*   adj     = (const int*)  d_in[2];
  const float* W1_seg  = (const float*)d_in[3];
  const float* b1_seg  = (const float*)d_in[4];
  const float* g1_seg  = (const float*)d_in[5];
  const float* bt1_seg = (const float*)d_in[6];
  const float* W2_seg  = (const float*)d_in[7];
  const float* b2_seg  = (const float*)d_in[8];
  const float* g2_seg  = (const float*)d_in[9];
  const float* bt2_seg = (const float*)d_in[10];
  const float* W1_sp   = (const float*)d_in[11];
  const float* b1_sp   = (const float*)d_in[12];
  const float* g1_sp   = (const float*)d_in[13];
  const float* bt1_sp  = (const float*)d_in[14];
  const float* W2_sp   = (const float*)d_in[15];
  const float* b2_sp   = (const float*)d_in[16];
  const float* g2_sp   = (const float*)d_in[17];
  const float* bt2_sp  = (const float*)d_in[18];
  const float* Wg1     = (const float*)d_in[19];
  const float* Wg2     = (const float*)d_in[20];
  const float* a_vec   = (const float*)d_in[21];
  const float* Wd      = (const float*)d_in[22];
  const float* bd      = (const float*)d_in[23];
  float* out = (float*)d_out;

  float* ws    = (float*)d_ws;
  float* xs1   = ws;                 // 524288 floats
  float* xs2   = ws + 524288;        // 524288
  float* gbuf  = ws + 1048576;       // 1048576
  float* hpbuf = ws + 2097152;       // 1048576
  float* sibuf = ws + 3145728;       // 8192
  float* sjbuf = ws + 3153920;       // 8192
  float* ys1   = ws + 3162112;       // 128
  float* cvec  = ws + 3162240;       // 256
  short* gTbuf = (short*)(ws + 3162496);   // 2*128*4096 bf16 = 2 MB
  short* w1T   = (short*)(ws + 3686784);   // 64*4096 bf16 = 512 KB

  prep_w1_kernel<<<64, 256, 0, stream>>>(W1_seg, w1T);
  gemm1_mfma_kernel<<<512, 256, 0, stream>>>(x, w1T, b1_seg, xs1);
  bn_elu_kernel<<<1024, 256, 0, stream>>>(xs1, xs1, g1_seg, bt1_seg, 262144);
  gemm2_kernel<<<128, 256, 0, stream>>>(xs1, W2_seg, b2_seg, xs2);
  bn_elu_kernel<<<1024, 256, 0, stream>>>(xs2, xs2, g2_seg, bt2_seg, 262144);
  sp1_kernel<<<128, 256, 0, stream>>>(y, W1_sp, b1_sp, ys1);
  sp2_kernel<<<1, 256, 0, stream>>>(ys1, g1_sp, bt1_sp, W2_sp, b2_sp, g2_sp, bt2_sp, Wg1, cvec);
  gemm3_kernel<<<128, 256, 0, stream>>>(xs2, Wg1, cvec, gbuf);
  transpose_g_kernel<<<dim3(64, 2), 256, 0, stream>>>(gbuf, gTbuf);
  sisj_kernel<<<2048, 256, 0, stream>>>(gbuf, a_vec, sibuf, sjbuf);
  att_mfma_kernel<<<dim3(256, 2), 256, 0, stream>>>(adj, sibuf, sjbuf, gTbuf, hpbuf);
  final_kernel<<<8192, 128, 0, stream>>>(hpbuf, Wg2, Wd, bd, out);
}